// Round 1
// baseline (1349.136 us; speedup 1.0000x reference)
//
#include <hip/hip_runtime.h>
#include <hip/hip_bf16.h>

// ---------------------------------------------------------------------------
// QuestionGuidedGraphAttention on MI355X
//
// att_n = segsoftmax( tanh(nodes@W_n + (question@W_nq + b_nq + b_n)[gid]) @ w_nv + b_nv )
// att_e = same for edges.
//
// Plan:
//  1. prep_wt:  W_n/W_e [512,512] fp32 -> Wt bf16 transposed [p][k] (B^T GEMM input)
//  2. prep_q :  Qp[b][p] = question@W_q + b_q + b_h  (fp32, k-split + atomics)
//  3. fused_gemm_attn (x2): BM=32 rows x N=512 full width per block, BK=32,
//     bf16 MFMA 16x16x32, fused tanh/w-dot/exp epilogue, z via LDS+global atomics.
//     A (nodes/edges) is read from HBM exactly once.
//  4. norm: att = e / z[gid]
// ---------------------------------------------------------------------------

typedef __attribute__((ext_vector_type(4))) float  floatx4;
typedef __attribute__((ext_vector_type(8))) short  shortx8;

#define TN_CONST 131072
#define TE_CONST 262144

__device__ __forceinline__ unsigned short f2bf(float f) {
    union { float f; unsigned u; } v; v.f = f;
    unsigned u = v.u;
    unsigned r = (u + 0x7FFFu + ((u >> 16) & 1u)) >> 16;   // RNE
    return (unsigned short)r;
}

// --- W transpose + bf16 convert: Wt[p][k] = bf16(W[k][p]) --------------------
__global__ void prep_wt_kernel(const float* __restrict__ Wn, const float* __restrict__ We,
                               unsigned short* __restrict__ Wtn, unsigned short* __restrict__ Wte)
{
    int c = blockIdx.x * 256 + threadIdx.x;      // 0 .. 2*262144-1
    const int sel = c >> 18;
    const int idx = c & 262143;
    const int p = idx >> 9, k = idx & 511;
    const float* W = sel ? We : Wn;
    unsigned short* Wt = sel ? Wte : Wtn;
    Wt[idx] = f2bf(W[(size_t)k * 512 + p]);
}

// --- Qp[b][p] = sum_k question[b][k]*Wq[k][p] + bq[p] + bh[p]  (atomic k-split)
__global__ void prep_q_kernel(const float* __restrict__ question,
                              const float* __restrict__ Wnq, const float* __restrict__ bnq,
                              const float* __restrict__ bn,
                              const float* __restrict__ Weq, const float* __restrict__ beq,
                              const float* __restrict__ be,
                              float* __restrict__ Qpn, float* __restrict__ Qpe)
{
    const int b     = blockIdx.x;    // 0..63
    const int which = blockIdx.y;    // 0=n 1=e
    const int kc    = blockIdx.z;    // 0..3 (chunks of 192)
    const int p     = threadIdx.x;   // 0..511
    const float* W  = which ? Weq : Wnq;
    const float* bq = which ? beq : bnq;
    const float* bh = which ? be  : bn;
    float* Qp       = which ? Qpe : Qpn;
    const float* q  = question + b * 768;
    float s = 0.f;
    const int kbeg = kc * 192, kend = kbeg + 192;
    for (int k = kbeg; k < kend; ++k) s += q[k] * W[(size_t)k * 512 + p];
    if (kc == 0) s += bq[p] + bh[p];
    atomicAdd(&Qp[b * 512 + p], s);
}

// --- main fused kernel -------------------------------------------------------
// grid.x = M/32 blocks, 256 threads (4 waves). Each block: rows r0..r0+31, all
// 512 output columns. Wave w owns columns [w*128, w*128+128) as 2x8 frags.
#define BM 32
#define BKK 32

__global__ __launch_bounds__(256, 3)
void fused_gemm_attn(const float* __restrict__ A,          // [M][512] fp32
                     const unsigned short* __restrict__ Bt, // [512][512] bf16, Bt[p][k]
                     const float* __restrict__ Qp,          // [64][512] fp32 (biases folded)
                     const float* __restrict__ wv,          // [512]
                     const float* __restrict__ bvp,         // scalar
                     const int*   __restrict__ gid,         // [M]
                     float* __restrict__ eout,              // [M]  exp(s) out
                     float* __restrict__ zglob)             // [64] segment sums
{
    __shared__ unsigned short As[BM][BKK + 8];     // 32x40  (+8 pad: 80B stride)
    __shared__ unsigned short Bs[512][BKK + 8];    // 512x40
    __shared__ float sred[4][BM];
    __shared__ float zpart[64];

    const int tid  = threadIdx.x;
    const int wave = tid >> 6;
    const int lane = tid & 63;
    const int m16  = lane & 15;
    const int q4   = lane >> 4;
    const long r0  = (long)blockIdx.x * BM;

    floatx4 acc[2][8];
#pragma unroll
    for (int i = 0; i < 2; ++i)
#pragma unroll
        for (int j = 0; j < 8; ++j) acc[i][j] = (floatx4){0.f, 0.f, 0.f, 0.f};

    // A staging: 32x32 fp32 tile = 256 float4 chunks, one per thread
    const int ar  = tid >> 3;          // row 0..31
    const int akc = (tid & 7) << 2;    // k offset 0,4,..28
    const float* aptr = A + (size_t)(r0 + ar) * 512 + akc;

    for (int k0 = 0; k0 < 512; k0 += BKK) {
        __syncthreads();
        { // stage A (fp32 -> bf16)
            const float4 v = *(const float4*)(aptr + k0);
            unsigned lo = ((unsigned)f2bf(v.y) << 16) | f2bf(v.x);
            unsigned hi = ((unsigned)f2bf(v.w) << 16) | f2bf(v.z);
            *(uint2*)&As[ar][akc] = make_uint2(lo, hi);
        }
        // stage B: 512x32 bf16 = 2048 chunks of 8 bf16, 8 per thread
#pragma unroll
        for (int i = 0; i < 8; ++i) {
            int c   = tid + i * 256;       // 0..2047
            int br  = c >> 2;              // p row 0..511
            int bkc = (c & 3) << 3;        // 0,8,16,24
            uint4 v = *(const uint4*)(Bt + (size_t)br * 512 + k0 + bkc);
            *(uint4*)&Bs[br][bkc] = v;
        }
        __syncthreads();

        shortx8 af[2], bfr[8];
#pragma unroll
        for (int i = 0; i < 2; ++i)
            af[i] = *(const shortx8*)&As[i * 16 + m16][q4 * 8];
#pragma unroll
        for (int j = 0; j < 8; ++j)
            bfr[j] = *(const shortx8*)&Bs[wave * 128 + j * 16 + m16][q4 * 8];
#pragma unroll
        for (int i = 0; i < 2; ++i)
#pragma unroll
            for (int j = 0; j < 8; ++j)
                acc[i][j] = __builtin_amdgcn_mfma_f32_16x16x32_bf16(af[i], bfr[j], acc[i][j], 0, 0, 0);
    }

    // epilogue: s[row] = sum_p tanh(h + Qp[g][p]) * wv[p]
    // C/D layout: col = lane&15, row = (lane>>4)*4 + reg   [verified m89/m91]
    const float bv = bvp[0];
#pragma unroll
    for (int i = 0; i < 2; ++i) {
#pragma unroll
        for (int reg = 0; reg < 4; ++reg) {
            const int row = i * 16 + q4 * 4 + reg;
            const int g   = gid[r0 + row];
            const float* qrow = Qp + (size_t)g * 512;
            float partial = 0.f;
#pragma unroll
            for (int j = 0; j < 8; ++j) {
                const int p = wave * 128 + j * 16 + m16;
                float h  = acc[i][j][reg] + qrow[p];
                float ex = __expf(2.f * h);                                // tanh
                float t  = (ex - 1.f) * __builtin_amdgcn_rcpf(ex + 1.f);
                partial += t * wv[p];
            }
            partial += __shfl_xor(partial, 1);
            partial += __shfl_xor(partial, 2);
            partial += __shfl_xor(partial, 4);
            partial += __shfl_xor(partial, 8);
            if (m16 == 0) sred[wave][row] = partial;   // per-wave 128-col partial
        }
    }
    if (tid < 64) zpart[tid] = 0.f;
    __syncthreads();
    if (tid < BM) {
        float s = sred[0][tid] + sred[1][tid] + sred[2][tid] + sred[3][tid] + bv;
        float e = __expf(s);                       // no max-subtract: |s| <~ 2
        eout[r0 + tid] = e;
        atomicAdd(&zpart[gid[r0 + tid]], e);
    }
    __syncthreads();
    if (tid < 64) {
        float v = zpart[tid];
        if (v != 0.f) atomicAdd(&zglob[tid], v);
    }
}

// --- normalize: att = e / z[gid] --------------------------------------------
__global__ void norm_kernel(float* __restrict__ out, const int* __restrict__ ngid,
                            const int* __restrict__ egid, const float* __restrict__ z)
{
    int idx = blockIdx.x * 256 + threadIdx.x;     // 0..393215
    float zz;
    if (idx < TN_CONST) zz = z[ngid[idx]];
    else                zz = z[64 + egid[idx - TN_CONST]];
    out[idx] = out[idx] / zz;
}

extern "C" void kernel_launch(void* const* d_in, const int* in_sizes, int n_in,
                              void* d_out, int out_size, void* d_ws, size_t ws_size,
                              hipStream_t stream)
{
    const float* question = (const float*)d_in[0];
    const float* nodes    = (const float*)d_in[1];
    const float* edges    = (const float*)d_in[2];
    const float* W_nq     = (const float*)d_in[3];
    const float* b_nq     = (const float*)d_in[4];
    const float* W_n      = (const float*)d_in[5];
    const float* b_n      = (const float*)d_in[6];
    const float* w_nv     = (const float*)d_in[7];
    const float* b_nv     = (const float*)d_in[8];
    const float* W_eq     = (const float*)d_in[9];
    const float* b_eq     = (const float*)d_in[10];
    const float* W_e      = (const float*)d_in[11];
    const float* b_e      = (const float*)d_in[12];
    const float* w_ev     = (const float*)d_in[13];
    const float* b_ev     = (const float*)d_in[14];
    const int* node_gid   = (const int*)d_in[15];
    const int* edge_gid   = (const int*)d_in[16];
    float* out = (float*)d_out;

    // workspace layout (bytes):
    //   [0,512)              z[128]
    //   [512,131584)         Qpn [64*512] f32
    //   [131584,262656)      Qpe [64*512] f32
    //   [262656,786944)      Wtn [512*512] bf16
    //   [786944,1311232)     Wte [512*512] bf16
    char* ws = (char*)d_ws;
    float*          z   = (float*)(ws);
    float*          Qpn = (float*)(ws + 512);
    float*          Qpe = (float*)(ws + 131584);
    unsigned short* Wtn = (unsigned short*)(ws + 262656);
    unsigned short* Wte = (unsigned short*)(ws + 786944);

    hipMemsetAsync(ws, 0, 262656, stream);  // z + Qpn + Qpe

    prep_wt_kernel<<<2048, 256, 0, stream>>>(W_n, W_e, Wtn, Wte);
    prep_q_kernel<<<dim3(64, 2, 4), 512, 0, stream>>>(question, W_nq, b_nq, b_n,
                                                      W_eq, b_eq, b_e, Qpn, Qpe);
    fused_gemm_attn<<<TN_CONST / BM, 256, 0, stream>>>(nodes, Wtn, Qpn, w_nv, b_nv,
                                                       node_gid, out, z);
    fused_gemm_attn<<<TE_CONST / BM, 256, 0, stream>>>(edges, Wte, Qpe, w_ev, b_ev,
                                                       edge_gid, out + TN_CONST, z + 64);
    norm_kernel<<<1536, 256, 0, stream>>>(out, node_gid, edge_gid, z);
}